// Round 2
// baseline (78.743 us; speedup 1.0000x reference)
//
#include <hip/hip_runtime.h>
#include <hip/hip_bf16.h>
#include <stdint.h>

typedef __attribute__((ext_vector_type(8))) short short8;
typedef __attribute__((ext_vector_type(4))) float f32x4;

#define B_   16
#define C_   64
#define H_   112
#define W_   112
#define O_   128
#define HP   114
#define HWP  (HP*HP)          // 12996 padded plane
#define HW   (H_*W_)          // 12544
#define XPAD_BYTES ((size_t)B_*HWP*C_*2)   // 26,615,808
#define WBUF_BYTES (9*64*128*2)            // 147,456

__device__ __forceinline__ unsigned short f2bf(float f) {
    union { float f; uint32_t u; } v; v.f = f;
    uint32_t u = v.u;
    u += 0x7fffu + ((u >> 16) & 1u);   // round-to-nearest-even
    return (unsigned short)(u >> 16);
}

// ---------------- Pass 0a: x NCHW f32 -> padded NHWC bf16 ----------------
// One block per (b, h): reads 64 c-rows of 112 floats, writes 112 w-rows of
// 64 contiguous bf16 channels at (b, h+1, w+1, :).
__global__ void pad_transpose(const float* __restrict__ x,
                              unsigned short* __restrict__ xpad)
{
    __shared__ float tile[64][113];   // +1 pad: conflict-free column reads
    const int bh = blockIdx.x;
    const int b = bh / H_, h = bh % H_;
    const int t = threadIdx.x;

    const float* xr = x + ((size_t)b * C_ * HW) + (size_t)h * W_;  // x[b][0][h][0]
    #pragma unroll
    for (int i = 0; i < 28; ++i) {                 // 64*112 = 7168 = 28*256
        int flat = i * 256 + t;
        int c = flat / W_, w = flat % W_;
        tile[c][w] = xr[(size_t)c * HW + w];
    }
    __syncthreads();

    unsigned short* dst = xpad + ((size_t)(b * HP + h + 1) * HP + 1) * C_;  // (b,h+1,1,0)
    #pragma unroll
    for (int j = 0; j < 7; ++j) {                  // 112*16 = 1792 = 7*256
        int flat = j * 256 + t;
        int w = flat >> 4, c = (flat & 15) * 4;
        ushort4 v;
        v.x = f2bf(tile[c + 0][w]);
        v.y = f2bf(tile[c + 1][w]);
        v.z = f2bf(tile[c + 2][w]);
        v.w = f2bf(tile[c + 3][w]);
        *(ushort4*)(dst + (size_t)w * C_ + c) = v;
    }
}

// ---------------- Pass 0b: weight (c,kh,kw,o) f32 -> (kh,kw,o,c) bf16, pre-swizzled
// Swizzle: within each o-row (128 B = 8 chunks of 16B), chunk c16 stored at
// position c16 ^ (o & 7). GEMM stages this linearly into LDS and reads with
// the same XOR -> bank-conflict-free ds_read_b128.
__global__ void wtrans(const float* __restrict__ wt, char* __restrict__ wbuf)
{
    int idx = blockIdx.x * 256 + threadIdx.x;      // [0, 73728)
    int slice = idx >> 13;                         // kh*3+kw
    int rem = idx & 8191;
    int o = rem >> 6, c = rem & 63;
    int kh = slice / 3, kw = slice % 3;
    float f = wt[(((size_t)c * 3 + kh) * 3 + kw) * O_ + o];
    size_t dstb = (size_t)slice * 16384 + (size_t)o * 128
                + (size_t)(((c >> 3) ^ (o & 7)) << 4) + ((c & 7) << 1);
    *(unsigned short*)(wbuf + dstb) = f2bf(f);
}

// ---------------- Pass 1: implicit-GEMM conv, 128x128 tile, 4 waves ----------------
// M = 200704 (spatial), N = 128 (= all O), K = 9 steps of 64 channels.
// A tile: 128 rows x 64 ch bf16 (16 KB), per-lane pre-swizzled global src.
// B tile: 128 o x 64 ch bf16 (16 KB), linear copy of pre-swizzled wbuf.
__global__ __launch_bounds__(256, 2) void conv_gemm(
    const char* __restrict__ xpad,
    const char* __restrict__ wbuf,
    float* __restrict__ out)
{
    __shared__ char lds[32768];
    char* ldsA = lds;
    char* ldsB = lds + 16384;

    const int t = threadIdx.x;
    const int lane = t & 63, wid = t >> 6;
    const int wr = wid >> 1, wc = wid & 1;
    const int bid = blockIdx.x;
    const int b = bid / 98;                 // 12544/128 = 98 tiles per batch, exact
    const int ml0 = (bid % 98) * 128;

    // Per-lane A source pointers for the 4 staging issues of this wave.
    // Issue i covers rows r = wid*32 + i*8 + (lane>>3); 8 lanes = one 128B row.
    // Source chunk col is XORed with (r&7) so a LINEAR LDS write + XORed read
    // is bank-conflict-free (both-sides-or-neither rule, m173 pattern).
    const char* srcA[4];
    #pragma unroll
    for (int i = 0; i < 4; ++i) {
        int r = wid * 32 + i * 8 + (lane >> 3);
        int ml = ml0 + r;
        int h = ml / W_, w = ml - h * W_;
        srcA[i] = xpad + ((size_t)b * HWP + (size_t)h * HP + w) * 128
                + (((lane & 7) ^ (r & 7)) << 4);
    }

    f32x4 acc[4][4] = {};

    #pragma unroll
    for (int s = 0; s < 9; ++s) {
        const int kh = s / 3, kw = s % 3;
        const int shiftA = (kh * HP + kw) * 128;

        __syncthreads();   // previous tile's compute done before overwrite
        #pragma unroll
        for (int i = 0; i < 4; ++i) {
            __builtin_amdgcn_global_load_lds(
                (const __attribute__((address_space(1))) void*)(srcA[i] + shiftA),
                (__attribute__((address_space(3))) void*)(ldsA + (wid * 32 + i * 8) * 128),
                16, 0, 0);
        }
        const char* wsl = wbuf + s * 16384 + wid * 4096 + lane * 16;
        #pragma unroll
        for (int i = 0; i < 4; ++i) {
            __builtin_amdgcn_global_load_lds(
                (const __attribute__((address_space(1))) void*)(wsl + i * 1024),
                (__attribute__((address_space(3))) void*)(ldsB + wid * 4096 + i * 1024),
                16, 0, 0);
        }
        __syncthreads();   // vmcnt drained by compiler before barrier

        #pragma unroll
        for (int ks = 0; ks < 2; ++ks) {
            short8 av[4], bv[4];
            const int xr = ((ks * 4 + (lane >> 4)) ^ (lane & 7)) << 4;
            #pragma unroll
            for (int mf = 0; mf < 4; ++mf)
                av[mf] = *(const short8*)(ldsA + (wr * 64 + mf * 16 + (lane & 15)) * 128 + xr);
            #pragma unroll
            for (int nf = 0; nf < 4; ++nf)
                bv[nf] = *(const short8*)(ldsB + (wc * 64 + nf * 16 + (lane & 15)) * 128 + xr);
            #pragma unroll
            for (int mf = 0; mf < 4; ++mf)
                #pragma unroll
                for (int nf = 0; nf < 4; ++nf)
                    acc[mf][nf] = __builtin_amdgcn_mfma_f32_16x16x32_bf16(
                        av[mf], bv[nf], acc[mf][nf], 0, 0, 0);
        }
    }

    // Epilogue: C/D layout col=lane&15 (o), row=(lane>>4)*4+reg (m).
    // Each lane's 4 regs are 4 consecutive m -> float4 store into NCHW.
    const int oc = wc * 64 + (lane & 15);
    const int mrow = ml0 + wr * 64 + ((lane >> 4) << 2);
    #pragma unroll
    for (int mf = 0; mf < 4; ++mf) {
        #pragma unroll
        for (int nf = 0; nf < 4; ++nf) {
            float* dst = out + ((size_t)(b * O_ + oc + nf * 16) * HW) + mrow + mf * 16;
            *(f32x4*)dst = acc[mf][nf];
        }
    }
}

extern "C" void kernel_launch(void* const* d_in, const int* in_sizes, int n_in,
                              void* d_out, int out_size, void* d_ws, size_t ws_size,
                              hipStream_t stream) {
    const float* x  = (const float*)d_in[0];
    const float* wt = (const float*)d_in[1];
    float* out = (float*)d_out;
    char* xpad = (char*)d_ws;
    char* wbuf = (char*)d_ws + XPAD_BYTES;

    hipMemsetAsync(xpad, 0, XPAD_BYTES, stream);   // zero borders (capture-safe)
    hipLaunchKernelGGL(pad_transpose, dim3(B_ * H_), dim3(256), 0, stream,
                       x, (unsigned short*)xpad);
    hipLaunchKernelGGL(wtrans, dim3(288), dim3(256), 0, stream, wt, wbuf);
    hipLaunchKernelGGL(conv_gemm, dim3(1568), dim3(256), 0, stream,
                       xpad, wbuf, out);
}

// Round 4
// 64.108 us; speedup vs baseline: 1.2283x; 1.2283x over previous
//
#include <hip/hip_runtime.h>
#include <hip/hip_bf16.h>
#include <stdint.h>

typedef __attribute__((ext_vector_type(8))) short short8;
typedef __attribute__((ext_vector_type(4))) float f32x4;

#define B_   16
#define C_   64
#define H_   112
#define W_   112
#define O_   128
#define HP   114
#define HWP  (HP*HP)          // 12996 padded plane positions
#define HW   (H_*W_)          // 12544
#define XPAD_BYTES ((size_t)B_*HWP*C_*2)   // 26,615,808
#define NROWS 384             // staged A-union rows (need <=362)

__device__ __forceinline__ unsigned short f2bf(float f) {
    union { float f; uint32_t u; } v; v.f = f;
    uint32_t u = v.u;
    u += 0x7fffu + ((u >> 16) & 1u);   // round-to-nearest-even
    return (unsigned short)(u >> 16);
}

// ---------------- Pass 0a: x NCHW f32 -> padded NHWC bf16 (+ border zeroing) --------
// One block per (b, h): reads 64 c-rows of 112 floats, writes 112 w-rows of
// 64 contiguous bf16 channels at (b, h+1, w+1, :). Borders zeroed in-kernel
// (replaces the 26.6 MB hipMemsetAsync that cost ~60 us).
__global__ void pad_transpose(const float* __restrict__ x,
                              unsigned short* __restrict__ xpad)
{
    __shared__ float tile[64][113];   // +1 pad: conflict-free column reads
    const int bh = blockIdx.x;
    const int b = bh / H_, h = bh % H_;
    const int t = threadIdx.x;

    const float* xr = x + ((size_t)b * C_ * HW) + (size_t)h * W_;  // x[b][0][h][0]
    #pragma unroll
    for (int i = 0; i < 28; ++i) {                 // 64*112 = 7168 = 28*256
        int flat = i * 256 + t;
        int c = flat / W_, w = flat % W_;
        tile[c][w] = xr[(size_t)c * HW + w];
    }

    // Border zeroing (disjoint from interior writes):
    // w=0 and w=113 columns of row h+1
    if (t < 64) {
        size_t base = ((size_t)(b * HP + h + 1) * HP) * 64;
        xpad[base + t] = 0;                // (h+1, 0, ch t)
        xpad[base + (size_t)113 * 64 + t] = 0;     // (h+1, 113, ch t)
    }
    // full top/bottom halo rows
    if (h == 0 || h == 111) {
        const int row = (h == 0) ? 0 : 113;
        size_t base = ((size_t)(b * HP + row) * HP) * 64;   // elem index
        ushort4 z4; z4.x = z4.y = z4.z = z4.w = 0;
        for (int k = t; k < (HP * 64) / 4; k += 256)        // 1824 ushort4
            *(ushort4*)(xpad + base + (size_t)k * 4) = z4;
    }
    __syncthreads();

    unsigned short* dst = xpad + ((size_t)(b * HP + h + 1) * HP + 1) * C_;  // (b,h+1,1,0)
    #pragma unroll
    for (int j = 0; j < 7; ++j) {                  // 112*16 = 1792 = 7*256
        int flat = j * 256 + t;
        int w = flat >> 4, c = (flat & 15) * 4;
        ushort4 v;
        v.x = f2bf(tile[c + 0][w]);
        v.y = f2bf(tile[c + 1][w]);
        v.z = f2bf(tile[c + 2][w]);
        v.w = f2bf(tile[c + 3][w]);
        *(ushort4*)(dst + (size_t)w * C_ + c) = v;
    }
}

// ---------------- Pass 0b: weight (c,kh,kw,o) f32 -> fragment-ordered bf16 ----------
// Layout [s][ks][wc][nf][lane][j]: lane l of wave-half wc, fragment nf, k-slice ks
// reads its MFMA B-operand (o = wc*64+nf*16+(l&15), k = ks*32+(l>>4)*8+j) as one
// perfectly coalesced 1KB global_load_dwordx4 per (nf,ks). No LDS for B at all.
__global__ void wtrans(const float* __restrict__ wt, unsigned short* __restrict__ wbuf)
{
    int f = blockIdx.x * 256 + threadIdx.x;        // [0, 73728)
    int j    = f & 7;
    int lane = (f >> 3) & 63;
    int nf   = (f >> 9) & 3;
    int wc   = (f >> 11) & 1;
    int ks   = (f >> 12) & 1;
    int s    = f >> 13;
    int o = wc * 64 + nf * 16 + (lane & 15);
    int c = (ks * 4 + (lane >> 4)) * 8 + j;
    int kh = s / 3, kw = s % 3;
    wbuf[f] = f2bf(wt[(((size_t)c * 3 + kh) * 3 + kw) * O_ + o]);
}

// ---------------- Pass 1: implicit-GEMM conv, union-staged A, barrier-free K-loop ---
// M = 200704, N = 128 (= all O), K = 576. The 9 (kh,kw) A-tiles are shifted
// windows of one region: p = ml + 2*oh + (kh*114+kw). Stage the 384-row union
// ONCE (48 KB, XOR-swizzled via pre-swizzled global source), one barrier, then
// 288 MFMAs with zero barriers. B comes straight from L2 (147 KB resident).
__global__ __launch_bounds__(256, 2) void conv_gemm(
    const char* __restrict__ xpad,
    const char* __restrict__ wbuf,
    float* __restrict__ out)
{
    __shared__ char ldsA[NROWS * 128];   // 49152 B

    const int t = threadIdx.x;
    const int lane = t & 63, wid = t >> 6;
    const int wr = wid >> 1, wc = wid & 1;
    const int bid0 = blockIdx.x;
    const int bid = (bid0 & 7) * 196 + (bid0 >> 3);  // XCD swizzle, 1568 = 8*196 exact
    const int b = bid / 98;                 // 98 M-tiles per batch, exact
    const int ml0 = (bid % 98) * 128;
    const int oh0 = ml0 / W_;
    const int pbase = ml0 + 2 * oh0;        // first padded-plane row of the union

    // Stage A-union: 384 rows x 8 chunks = 3072 16B loads = 12 issues/thread.
    // LDS dst is wave-uniform (HW adds lane*16); source chunk pre-XORed by row
    // so linear LDS write + XORed ds_read is bank-spread (rule #21 pattern).
    const char* plane = xpad + (size_t)b * ((size_t)HWP * 128);
    #pragma unroll
    for (int i = 0; i < 12; ++i) {
        const int gbase = i * 256 + wid * 64;       // wave-uniform
        const int g = gbase + lane;
        const int r = g >> 3, ck = g & 7;
        __builtin_amdgcn_global_load_lds(
            (const __attribute__((address_space(1))) void*)
                (plane + (size_t)(pbase + r) * 128 + ((ck ^ (r & 7)) << 4)),
            (__attribute__((address_space(3))) void*)(ldsA + gbase * 16),
            16, 0, 0);
    }
    __syncthreads();   // single barrier: all MFMA data now in LDS

    // Per-fragment LDS base rows (per-lane): row = ml + 2*oh - pbase
    int rowb[4];
    #pragma unroll
    for (int mf = 0; mf < 4; ++mf) {
        int ml = ml0 + wr * 64 + mf * 16 + (lane & 15);
        int oh = ml / W_;
        rowb[mf] = ml + 2 * oh - pbase;
    }
    const int kq = lane >> 4;   // k-quarter 0..3

    f32x4 acc[4][4] = {};

    #pragma unroll
    for (int s = 0; s < 9; ++s) {
        const int kh = s / 3, kw = s % 3;
        const int soff = kh * HP + kw;

        // B fragments: 8 coalesced 1KB loads per wave from L2-resident wbuf
        short8 bv[2][4];
        const char* wb = (const char*)wbuf + s * 16384 + wc * 4096 + lane * 16;
        #pragma unroll
        for (int ks = 0; ks < 2; ++ks)
            #pragma unroll
            for (int nf = 0; nf < 4; ++nf)
                bv[ks][nf] = *(const short8*)(wb + ks * 8192 + nf * 1024);

        #pragma unroll
        for (int ks = 0; ks < 2; ++ks) {
            short8 av[4];
            #pragma unroll
            for (int mf = 0; mf < 4; ++mf) {
                const int lrow = rowb[mf] + soff;
                const int ck = (ks * 4 + kq) ^ (lrow & 7);
                av[mf] = *(const short8*)(ldsA + lrow * 128 + (ck << 4));
            }
            #pragma unroll
            for (int mf = 0; mf < 4; ++mf)
                #pragma unroll
                for (int nf = 0; nf < 4; ++nf)
                    acc[mf][nf] = __builtin_amdgcn_mfma_f32_16x16x32_bf16(
                        av[mf], bv[ks][nf], acc[mf][nf], 0, 0, 0);
        }
    }

    // Epilogue: C/D layout col=lane&15 (o), row=(lane>>4)*4+reg (m).
    // Each lane's 4 regs are 4 consecutive m -> float4 store into NCHW.
    const int oc = wc * 64 + (lane & 15);
    const int mrow = ml0 + wr * 64 + ((lane >> 4) << 2);
    #pragma unroll
    for (int mf = 0; mf < 4; ++mf) {
        #pragma unroll
        for (int nf = 0; nf < 4; ++nf) {
            float* dst = out + ((size_t)(b * O_ + oc + nf * 16) * HW) + mrow + mf * 16;
            *(f32x4*)dst = acc[mf][nf];
        }
    }
}

extern "C" void kernel_launch(void* const* d_in, const int* in_sizes, int n_in,
                              void* d_out, int out_size, void* d_ws, size_t ws_size,
                              hipStream_t stream) {
    const float* x  = (const float*)d_in[0];
    const float* wt = (const float*)d_in[1];
    float* out = (float*)d_out;
    char* xpad = (char*)d_ws;
    char* wbuf = (char*)d_ws + XPAD_BYTES;

    hipLaunchKernelGGL(pad_transpose, dim3(B_ * H_), dim3(256), 0, stream,
                       x, (unsigned short*)xpad);
    hipLaunchKernelGGL(wtrans, dim3(288), dim3(256), 0, stream,
                       wt, (unsigned short*)wbuf);
    hipLaunchKernelGGL(conv_gemm, dim3(1568), dim3(256), 0, stream,
                       xpad, wbuf, out);
}